// Round 9
// baseline (229.066 us; speedup 1.0000x reference)
//
#include <hip/hip_runtime.h>
#include <hip/hip_bf16.h>

// ---- types ----
typedef __bf16 bf16x8 __attribute__((ext_vector_type(8)));
typedef __bf16 bf16x4 __attribute__((ext_vector_type(4)));
typedef float  f32x4  __attribute__((ext_vector_type(4)));

#define MFMA16(a, b, c) __builtin_amdgcn_mfma_f32_16x16x32_bf16((a), (b), (c), 0, 0, 0)

// Problem constants
#define BATCH 16
#define SEQ   1024
#define VD    1024
#define TD    768
#define HDIM  512
#define MROWS (BATCH * SEQ)   // 16384

typedef __attribute__((address_space(1))) const unsigned int gas_uint;
typedef __attribute__((address_space(3))) unsigned int las_uint;

__device__ __forceinline__ void async_copy16(const void* g, void* l) {
    // global -> LDS DMA, 16B/lane; LDS dest = wave-uniform base + lane*16
    __builtin_amdgcn_global_load_lds((gas_uint*)g, (las_uint*)l, 16, 0, 0);
}

// ---------------------------------------------------------------------------
// Stage one 256x64 bf16 tile (2048 x 16B chunks, 512 threads, 4/thread) via
// DMA with chunk-XOR swizzle applied on the GLOBAL side (LDS side stays
// lane-linear). Row r holds its 8 chunks in slots permuted by r&7.
// ---------------------------------------------------------------------------
__device__ __forceinline__ void stage_tile256(const __bf16* __restrict__ src,
                                              size_t ld, int row0, int k0,
                                              __bf16* __restrict__ buf, int tid) {
#pragma unroll
    for (int i = 0; i < 4; ++i) {
        const int c = i * 512 + tid;          // chunk slot 0..2047
        const int r = c >> 3;                 // row 0..255
        const int g = (c & 7) ^ (r & 7);      // swizzled global chunk
        async_copy16(&src[(size_t)(row0 + r) * ld + k0 + g * 8],
                     &buf[(c & ~63) * 8]);
    }
}

// fragment read: row r, k-half h (0/1), quad fq -> chunk (h*4+fq)^(r&7)
__device__ __forceinline__ bf16x8 frag_read(const __bf16* __restrict__ buf,
                                            int r, int h, int fq) {
    return *reinterpret_cast<const bf16x8*>(&buf[(r * 8 + ((h * 4 + fq) ^ (r & 7))) * 8]);
}

// ---------------------------------------------------------------------------
// fp32 reg-staging of one 64-row CHUNK (i = 0..3) of a 256x64 A-tile, fused
// fp32->bf16. Per-phase: stA_chunk writes A(kt+1) chunk q into the dead
// 3rd buffer, ldA_chunk then reloads regs[2q..2q+1] with A(kt+2) chunk q
// (register WAR: stA's read precedes ldA's write in issue order). Plain C++
// loads -> the compiler tracks the load->read dependency and inserts exact
// vmcnt waits (the R8 lesson: opaque asm loads + register caps spill-corrupt).
// ---------------------------------------------------------------------------
__device__ __forceinline__ void ldA_chunk(const float* __restrict__ src, int K,
                                          int row0, int k0, int tid, int i,
                                          float4* regs) {
    const int c = i * 512 + tid;          // chunk 0..2047
    const int r = c >> 3;                 // row 0..255
    const int j = c & 7;                  // chunk-in-row (linear global)
    const float4* p = reinterpret_cast<const float4*>(src) +
                      (size_t)(row0 + r) * (K >> 2) + (k0 >> 2) + j * 2;
    regs[i * 2]     = p[0];
    regs[i * 2 + 1] = p[1];
}

__device__ __forceinline__ void stA_chunk(__bf16* __restrict__ buf, int tid,
                                          int i, const float4* regs) {
    const int c = i * 512 + tid;
    const int r = c >> 3;
    const int j = c & 7;
    const float4 x0 = regs[i * 2], x1 = regs[i * 2 + 1];
    bf16x8 q = {(__bf16)x0.x, (__bf16)x0.y, (__bf16)x0.z, (__bf16)x0.w,
                (__bf16)x1.x, (__bf16)x1.y, (__bf16)x1.z, (__bf16)x1.w};
    *reinterpret_cast<bf16x8*>(&buf[(r * 8 + (j ^ (r & 7))) * 8]) = q;
}

// ---------------------------------------------------------------------------
// Mini convert: ONLY Wv/Wt fp32 -> bf16 (3.5 MiB read) + vn2/tn2 zero tail.
// [FROZEN since round 5]
// ---------------------------------------------------------------------------
#define NC_WV (HDIM * VD / 4)          // 131072
#define NC_WT (HDIM * TD / 4)          // 98304
#define NW_PAIRS ((NC_WV + NC_WT) / 2)             // 114688
#define CONVW_BLOCKS (NW_PAIRS / 256)              // 448 (exact)
#define NZ_BLOCKS (2 * MROWS / 4 / 256)            // 32
#define CONVW_GRID (CONVW_BLOCKS + NZ_BLOCKS)      // 480

__global__ __launch_bounds__(256) void conv_w_kernel(
    const float* __restrict__ Wv, const float* __restrict__ Wt,
    __bf16* __restrict__ Wvb, __bf16* __restrict__ Wtb,
    float* __restrict__ n2z) {
    const int blk = blockIdx.x;
    if (blk >= CONVW_BLOCKS) {   // block-uniform branch: zeroing tail
        const int zi = (blk - CONVW_BLOCKS) * 256 + threadIdx.x;
        reinterpret_cast<float4*>(n2z)[zi] = float4{0.f, 0.f, 0.f, 0.f};
        return;
    }
    int k = (blk * 256 + threadIdx.x) * 2;   // even chunk index (NC_WV even)
    const float* src;
    __bf16* dst;
    if (k < NC_WV) { src = Wv; dst = Wvb; }
    else { k -= NC_WV; src = Wt; dst = Wtb; }
    const float4 x0 = reinterpret_cast<const float4*>(src)[k];
    const float4 x1 = reinterpret_cast<const float4*>(src)[k + 1];
    bf16x8 q = {(__bf16)x0.x, (__bf16)x0.y, (__bf16)x0.z, (__bf16)x0.w,
                (__bf16)x1.x, (__bf16)x1.y, (__bf16)x1.z, (__bf16)x1.w};
    reinterpret_cast<bf16x8*>(dst)[k >> 1] = q;
}

// ---------------------------------------------------------------------------
// Projection GEMM (NT), 256x256 tile, 512 threads (8 waves 2x4, wave 128x64),
// BK=64, 8-phase schedule with TRIPLE-BUFFERED A (160 KiB LDS total).
// [= the VERIFIED round-7 kernel (76us), ONE edit: B(kt+2) DMA issued at
//  PHASE 1 instead of the boundary -> ~3 phases extra flight for B.]
// Race audit: Bs[kt&1]'s only readers in tile kt are ph0's bfr reads, which
// complete before ph0's barrier; ph1 is past it. Retirement audit: B(kt+2)
// is retired by the compiler wait before tile kt+1's stA_chunk(q=2) (its
// regs were loaded AFTER B(kt+2) in issue order; in-order vmcnt retire),
// ahead of tile kt+2's reads. Boundary vmcnt(12) stays a correct bound
// (outstanding <= A(kt+2)x8 + B(kt+2)x4 = 12).
//   C[M][512] = X[M][K] * W[512][K]^T + bias -> bf16 + fused norm^2.
// ---------------------------------------------------------------------------
__global__ __launch_bounds__(512, 2) void proj_kernel(
    const float* __restrict__ Xv32, const __bf16* __restrict__ Wvb, const float* __restrict__ bv_,
    const float* __restrict__ Xt32, const __bf16* __restrict__ Wtb, const float* __restrict__ bt_,
    __bf16* __restrict__ vout, __bf16* __restrict__ tout,
    float* __restrict__ vn2, float* __restrict__ tn2)
{
    __shared__ __bf16 As[3][256 * 64];   // 96 KiB (triple buffer)
    __shared__ __bf16 Bs[2][256 * 64];   // 64 KiB -> 160 KiB total (CU max)

    const int L  = blockIdx.x;
    const int x  = L & 7;                // XCD
    const int s  = L >> 3;               // 0..31
    const int z  = s >> 4;               // 0 = visual, 1 = text
    const int ss = s & 15;
    const int m0 = (x * 8 + (ss >> 1)) * 256;
    const int n0 = (ss & 1) * 256;

    const float* X; const __bf16* Wb; const float* bias; __bf16* out; float* n2; int K;
    if (z == 0) { X = Xv32; Wb = Wvb; bias = bv_; out = vout; n2 = vn2; K = VD; }
    else        { X = Xt32; Wb = Wtb; bias = bt_; out = tout; n2 = tn2; K = TD; }

    const int tid  = threadIdx.x;
    const int lane = tid & 63;
    const int wave = tid >> 6;
    const int wr   = wave >> 2;          // 0..1  (128-row half)
    const int wc   = wave & 3;           // 0..3  (64-col quarter)
    const int fr   = lane & 15;
    const int fq   = lane >> 4;

    f32x4 acc[8][4] = {};
    const int NKT = K >> 6;              // 16 (v) / 12 (t), block-uniform

    float4 regs[8];                      // A(next-next) raw fp32, 32 VGPR
    // prologue: A0 via regs+cvt into As[0]; A1 loaded into regs; B0/B1 DMA.
    {
        float4 rA0[8];
        ldA_chunk(X, K, m0, 0, tid, 0, rA0);
        ldA_chunk(X, K, m0, 0, tid, 1, rA0);
        ldA_chunk(X, K, m0, 0, tid, 2, rA0);
        ldA_chunk(X, K, m0, 0, tid, 3, rA0);
        stage_tile256(Wb, K, n0, 0,  Bs[0], tid);
        stage_tile256(Wb, K, n0, 64, Bs[1], tid);
        // compiler auto-waits retire A0 (oldest 8) before the cvt reads;
        // B0/B1 DMAs (newer) stay in flight.
        stA_chunk(As[0], tid, 0, rA0);
        stA_chunk(As[0], tid, 1, rA0);
        stA_chunk(As[0], tid, 2, rA0);
        stA_chunk(As[0], tid, 3, rA0);
        if (1 < NKT) {
            ldA_chunk(X, K, m0, 64, tid, 0, regs);
            ldA_chunk(X, K, m0, 64, tid, 1, regs);
            ldA_chunk(X, K, m0, 64, tid, 2, regs);
            ldA_chunk(X, K, m0, 64, tid, 3, regs);
        }
        // queue: [B0 x4, B1 x4, A1 x8] -> vmcnt(12) retires B0.
        asm volatile("s_waitcnt vmcnt(12)" ::: "memory");
        asm volatile("s_waitcnt lgkmcnt(0)" ::: "memory");
        __builtin_amdgcn_s_barrier();
    }

    int ar = 0, aw = 1;                  // A read/write buffer indices (mod 3)
    for (int kt = 0; kt < NKT; ++kt) {
        const __bf16* Ab = As[ar];
        const __bf16* Bb = Bs[kt & 1];
        const int doW = (kt + 1 < NKT);  // write A(kt+1) this tile
        const int doL = (kt + 2 < NKT);  // load  A(kt+2) / stage B(kt+2)
        bf16x8 bfr[4][2];                // B frags live across all 4 phases
#pragma unroll
        for (int q = 0; q < 4; ++q) {    // phase q: m-frags {2q,2q+1} x 4n x 2kh = 16 MFMA
            bf16x8 afr[2][2];
#pragma unroll
            for (int m2 = 0; m2 < 2; ++m2)
#pragma unroll
                for (int h = 0; h < 2; ++h)
                    afr[m2][h] = frag_read(Ab, wr * 128 + (q * 2 + m2) * 16 + fr, h, fq);
            if (q == 0) {
#pragma unroll
                for (int n = 0; n < 4; ++n)
#pragma unroll
                    for (int h = 0; h < 2; ++h)
                        bfr[n][h] = frag_read(Bb, wc * 64 + n * 16 + fr, h, fq);
            }
            // distributed A staging (uniform guards; regs WAR by issue order)
            if (doW) stA_chunk(As[aw], tid, q, regs);
            if (doL) ldA_chunk(X, K, m0, (kt + 2) << 6, tid, q, regs);
            // EARLY B-issue (the one change vs round 7): Bs[kt&1]'s readers
            // (ph0 bfr) are behind ph0's barrier -> safe to overwrite here.
            if (q == 1 && doL)
                stage_tile256(Wb, K, n0, (kt + 2) << 6, Bs[kt & 1], tid);
            __builtin_amdgcn_s_barrier();           // phase-entry lockstep
            __builtin_amdgcn_s_setprio(1);
#pragma unroll
            for (int h = 0; h < 2; ++h)
#pragma unroll
                for (int m2 = 0; m2 < 2; ++m2)
#pragma unroll
                    for (int n = 0; n < 4; ++n)
                        acc[q * 2 + m2][n] = MFMA16(afr[m2][h], bfr[n][h], acc[q * 2 + m2][n]);
            __builtin_amdgcn_s_setprio(0);
        }
        // K-tile boundary (no staging lump, no drain-to-0 mid-loop)
        if (kt < NKT - 1) {
            __builtin_amdgcn_s_barrier();           // Bs[kt&1]/As[ar] reads done
            __builtin_amdgcn_sched_barrier(0);
            if (kt + 2 < NKT) {
                // outstanding <= [A(kt+2) x8, B(kt+2) x4] = 12
                asm volatile("s_waitcnt vmcnt(12)" ::: "memory");
            } else {
                asm volatile("s_waitcnt vmcnt(0)" ::: "memory");   // final drain
            }
            asm volatile("s_waitcnt lgkmcnt(0)" ::: "memory");     // A writes visible
            __builtin_amdgcn_sched_barrier(0);
            __builtin_amdgcn_s_barrier();           // tile kt+1 fully resident
            ar = aw;
            aw = (aw == 2) ? 0 : aw + 1;
        }
    }

    // epilogue: +bias, bf16 store, fused partial row-norm^2
    float bc[4];
#pragma unroll
    for (int n = 0; n < 4; ++n)
        bc[n] = bias[n0 + wc * 64 + n * 16 + fr];

#pragma unroll
    for (int mf = 0; mf < 8; ++mf) {
        const int rowb = m0 + wr * 128 + mf * 16 + fq * 4;
#pragma unroll
        for (int r = 0; r < 4; ++r) {
            float s_ = 0.f;
#pragma unroll
            for (int n = 0; n < 4; ++n) {
                const float e = acc[mf][n][r] + bc[n];
                out[(size_t)(rowb + r) * HDIM + n0 + wc * 64 + n * 16 + fr] = (__bf16)e;
                s_ = fmaf(e, e, s_);
            }
            s_ += __shfl_xor(s_, 1);
            s_ += __shfl_xor(s_, 2);
            s_ += __shfl_xor(s_, 4);
            s_ += __shfl_xor(s_, 8);
            if (fr == 0) atomicAdd(&n2[rowb + r], s_);
        }
    }
}

// ---------------------------------------------------------------------------
// Batched dots GEMM (NT) -- 256x256 tile, 512 threads (8 waves 2x4, wave
// 128x64), BK=64, K=512 -> 8 K-tiles, double-buffered DMA staging with
// COUNTED vmcnt (T4) + 4-phase MFMA split + setprio (T3/T5) + raw s_barrier
// only.  out[b][i][j] = v.t / max(sqrt(vn2_i*tn2_j), eps)
// Grid: 256 blocks = 1/CU; XCD x owns batches {2x, 2x+1} (4MB = its L2).
// [FROZEN since round 2 -- control kernel]
// ---------------------------------------------------------------------------
__global__ __launch_bounds__(512, 2) void dots_kernel(const __bf16* __restrict__ v,
                                                      const __bf16* __restrict__ t,
                                                      const float* __restrict__ vn2,
                                                      const float* __restrict__ tn2,
                                                      float* __restrict__ out) {
    __shared__ __bf16 As[2][256 * 64];   // 64 KiB
    __shared__ __bf16 Bs[2][256 * 64];   // 64 KiB

    const int L  = blockIdx.x;
    const int x  = L & 7;
    const int s  = L >> 3;               // 0..31 within XCD
    const int b  = x * 2 + (s >> 4);     // batch
    const int i0 = ((s >> 2) & 3) * 256;
    const int j0 = (s & 3) * 256;

    const __bf16* vb = v + (size_t)b * SEQ * HDIM;
    const __bf16* tb = t + (size_t)b * SEQ * HDIM;

    const int tid  = threadIdx.x;
    const int lane = tid & 63;
    const int wave = tid >> 6;
    const int wr   = wave >> 2;          // 0..1  (128-row half)
    const int wc   = wave & 3;           // 0..3  (64-col quarter)
    const int fr   = lane & 15;
    const int fq   = lane >> 4;

    f32x4 acc[8][4] = {};
    const int NKT = HDIM >> 6;           // 8

    // prologue: stage K-tiles 0 and 1 (8 DMA loads/thread each)
    stage_tile256(vb, HDIM, i0, 0,  As[0], tid);
    stage_tile256(tb, HDIM, j0, 0,  Bs[0], tid);
    stage_tile256(vb, HDIM, i0, 64, As[1], tid);
    stage_tile256(tb, HDIM, j0, 64, Bs[1], tid);
    asm volatile("s_waitcnt vmcnt(8)" ::: "memory");  // K-tile 0 landed (in-order retire)
    __builtin_amdgcn_s_barrier();                     // all waves' tile-0 loads drained

    for (int kt = 0; kt < NKT; ++kt) {
        const __bf16* Ab = As[kt & 1];
        const __bf16* Bb = Bs[kt & 1];
        bf16x8 bfr[4][2];                // B frags live across all 4 phases
#pragma unroll
        for (int q = 0; q < 4; ++q) {    // phase q: m-frags {2q, 2q+1} x 4n x 2kh = 16 MFMA
            bf16x8 afr[2][2];
#pragma unroll
            for (int m2 = 0; m2 < 2; ++m2)
#pragma unroll
                for (int h = 0; h < 2; ++h)
                    afr[m2][h] = frag_read(Ab, wr * 128 + (q * 2 + m2) * 16 + fr, h, fq);
            if (q == 0) {
#pragma unroll
                for (int n = 0; n < 4; ++n)
#pragma unroll
                    for (int h = 0; h < 2; ++h)
                        bfr[n][h] = frag_read(Bb, wc * 64 + n * 16 + fr, h, fq);
            }
            __builtin_amdgcn_s_barrier();           // phase-entry lockstep
            __builtin_amdgcn_s_setprio(1);
#pragma unroll
            for (int h = 0; h < 2; ++h)
#pragma unroll
                for (int m2 = 0; m2 < 2; ++m2)
#pragma unroll
                    for (int n = 0; n < 4; ++n)
                        acc[q * 2 + m2][n] = MFMA16(afr[m2][h], bfr[n][h], acc[q * 2 + m2][n]);
            __builtin_amdgcn_s_setprio(0);
        }
        // K-tile boundary: buf[kt&1] fully consumed by ALL waves after this barrier.
        if (kt < NKT - 1) {
            __builtin_amdgcn_s_barrier();           // end of reads of buf[kt&1]
            __builtin_amdgcn_sched_barrier(0);
            if (kt + 2 < NKT) {
                const int kk = (kt + 2) << 6;
                stage_tile256(vb, HDIM, i0, kk, As[kt & 1], tid);
                stage_tile256(tb, HDIM, j0, kk, Bs[kt & 1], tid);
                // outstanding: stage(kt+1)=8 (oldest) + stage(kt+2)=8.
                // Leave kt+2 in flight across the whole next K-tile (T4).
                asm volatile("s_waitcnt vmcnt(8)" ::: "memory");
            } else {
                asm volatile("s_waitcnt vmcnt(0)" ::: "memory");
            }
            __builtin_amdgcn_sched_barrier(0);
            __builtin_amdgcn_s_barrier();           // all waves drained kt+1
        }
    }

    // epilogue: normalize and store fp32 output
    float vr2[8][4];
#pragma unroll
    for (int mf = 0; mf < 8; ++mf)
#pragma unroll
        for (int r = 0; r < 4; ++r)
            vr2[mf][r] = vn2[b * SEQ + i0 + wr * 128 + mf * 16 + fq * 4 + r];

    float* outb = out + ((size_t)b << 20);
#pragma unroll
    for (int n = 0; n < 4; ++n) {
        const int j     = j0 + wc * 64 + n * 16 + fr;
        const float tj2 = tn2[b * SEQ + j];
#pragma unroll
        for (int mf = 0; mf < 8; ++mf) {
            const int ib = i0 + wr * 128 + mf * 16 + fq * 4;
#pragma unroll
            for (int r = 0; r < 4; ++r) {
                const float denom = fmaxf(sqrtf(vr2[mf][r] * tj2), 1e-8f);
                outb[(size_t)(ib + r) * SEQ + j] = acc[mf][n][r] * __builtin_amdgcn_rcpf(denom);
            }
        }
    }
}

// ---------------------------------------------------------------------------
extern "C" void kernel_launch(void* const* d_in, const int* in_sizes, int n_in,
                              void* d_out, int out_size, void* d_ws, size_t ws_size,
                              hipStream_t stream) {
    const float* Xv = (const float*)d_in[0];
    const float* Xt = (const float*)d_in[1];
    const float* Wv = (const float*)d_in[2];
    const float* bv = (const float*)d_in[3];
    const float* Wt = (const float*)d_in[4];
    const float* bt = (const float*)d_in[5];
    float* out = (float*)d_out;

    char* ws = (char*)d_ws;
    size_t off = 0;
    __bf16* v   = (__bf16*)(ws + off); off += (size_t)MROWS * HDIM * 2;    // 16 MiB
    __bf16* t   = (__bf16*)(ws + off); off += (size_t)MROWS * HDIM * 2;    // 16 MiB
    __bf16* Wvb = (__bf16*)(ws + off); off += (size_t)HDIM * VD * 2;       // 1 MiB
    __bf16* Wtb = (__bf16*)(ws + off); off += (size_t)HDIM * TD * 2;       // 0.75 MiB
    float*  vn2 = (float*)(ws + off);  off += (size_t)MROWS * 4;           // 64 KiB
    float*  tn2 = (float*)(ws + off);  off += (size_t)MROWS * 4;           // 64 KiB (contiguous after vn2)

    // 0) W fp32 -> bf16 (tiny) + vn2/tn2 zero tail
    conv_w_kernel<<<CONVW_GRID, 256, 0, stream>>>(Wv, Wt, Wvb, Wtb, vn2);

    // 1) projections + fused norms (X converted in-staging): 256 blocks x 512
    proj_kernel<<<256, 512, 0, stream>>>(Xv, Wvb, bv, Xt, Wtb, bt, v, t, vn2, tn2);

    // 2) batched dots + normalize: 256 swizzled blocks of 512 threads
    dots_kernel<<<256, 512, 0, stream>>>(v, t, vn2, tn2, out);
}

// Round 10
// 222.757 us; speedup vs baseline: 1.0283x; 1.0283x over previous
//
#include <hip/hip_runtime.h>
#include <hip/hip_bf16.h>

// ---- types ----
typedef __bf16 bf16x8 __attribute__((ext_vector_type(8)));
typedef __bf16 bf16x4 __attribute__((ext_vector_type(4)));
typedef float  f32x4  __attribute__((ext_vector_type(4)));

#define MFMA16(a, b, c) __builtin_amdgcn_mfma_f32_16x16x32_bf16((a), (b), (c), 0, 0, 0)

// Problem constants
#define BATCH 16
#define SEQ   1024
#define VD    1024
#define TD    768
#define HDIM  512
#define MROWS (BATCH * SEQ)   // 16384

typedef __attribute__((address_space(1))) const unsigned int gas_uint;
typedef __attribute__((address_space(3))) unsigned int las_uint;

__device__ __forceinline__ void async_copy16(const void* g, void* l) {
    // global -> LDS DMA, 16B/lane; LDS dest = wave-uniform base + lane*16
    __builtin_amdgcn_global_load_lds((gas_uint*)g, (las_uint*)l, 16, 0, 0);
}

// ---------------------------------------------------------------------------
// Stage one 256x64 bf16 tile (2048 x 16B chunks, 512 threads, 4/thread) via
// DMA with chunk-XOR swizzle applied on the GLOBAL side (LDS side stays
// lane-linear). Row r holds its 8 chunks in slots permuted by r&7.
// ---------------------------------------------------------------------------
__device__ __forceinline__ void stage_tile256(const __bf16* __restrict__ src,
                                              size_t ld, int row0, int k0,
                                              __bf16* __restrict__ buf, int tid) {
#pragma unroll
    for (int i = 0; i < 4; ++i) {
        const int c = i * 512 + tid;          // chunk slot 0..2047
        const int r = c >> 3;                 // row 0..255
        const int g = (c & 7) ^ (r & 7);      // swizzled global chunk
        async_copy16(&src[(size_t)(row0 + r) * ld + k0 + g * 8],
                     &buf[(c & ~63) * 8]);
    }
}

// fragment read: row r, k-half h (0/1), quad fq -> chunk (h*4+fq)^(r&7)
__device__ __forceinline__ bf16x8 frag_read(const __bf16* __restrict__ buf,
                                            int r, int h, int fq) {
    return *reinterpret_cast<const bf16x8*>(&buf[(r * 8 + ((h * 4 + fq) ^ (r & 7))) * 8]);
}

// ---------------------------------------------------------------------------
// fp32 reg-staging of one 64-row CHUNK (i = 0..3) of a 256x64 A-tile, fused
// fp32->bf16. Plain C++ loads -> the compiler tracks load->read dependencies
// and inserts exact vmcnt waits (R8 lesson: opaque asm loads + register caps
// spill-corrupt).
// ---------------------------------------------------------------------------
__device__ __forceinline__ void ldA_chunk(const float* __restrict__ src, int K,
                                          int row0, int k0, int tid, int i,
                                          float4* regs) {
    const int c = i * 512 + tid;          // chunk 0..2047
    const int r = c >> 3;                 // row 0..255
    const int j = c & 7;                  // chunk-in-row (linear global)
    const float4* p = reinterpret_cast<const float4*>(src) +
                      (size_t)(row0 + r) * (K >> 2) + (k0 >> 2) + j * 2;
    regs[i * 2]     = p[0];
    regs[i * 2 + 1] = p[1];
}

__device__ __forceinline__ void stA_chunk(__bf16* __restrict__ buf, int tid,
                                          int i, const float4* regs) {
    const int c = i * 512 + tid;
    const int r = c >> 3;
    const int j = c & 7;
    const float4 x0 = regs[i * 2], x1 = regs[i * 2 + 1];
    bf16x8 q = {(__bf16)x0.x, (__bf16)x0.y, (__bf16)x0.z, (__bf16)x0.w,
                (__bf16)x1.x, (__bf16)x1.y, (__bf16)x1.z, (__bf16)x1.w};
    *reinterpret_cast<bf16x8*>(&buf[(r * 8 + (j ^ (r & 7))) * 8]) = q;
}

// ---------------------------------------------------------------------------
// Mini convert: ONLY Wv/Wt fp32 -> bf16 (3.5 MiB read) + vn2/tn2 zero tail.
// [FROZEN since round 5]
// ---------------------------------------------------------------------------
#define NC_WV (HDIM * VD / 4)          // 131072
#define NC_WT (HDIM * TD / 4)          // 98304
#define NW_PAIRS ((NC_WV + NC_WT) / 2)             // 114688
#define CONVW_BLOCKS (NW_PAIRS / 256)              // 448 (exact)
#define NZ_BLOCKS (2 * MROWS / 4 / 256)            // 32
#define CONVW_GRID (CONVW_BLOCKS + NZ_BLOCKS)      // 480

__global__ __launch_bounds__(256) void conv_w_kernel(
    const float* __restrict__ Wv, const float* __restrict__ Wt,
    __bf16* __restrict__ Wvb, __bf16* __restrict__ Wtb,
    float* __restrict__ n2z) {
    const int blk = blockIdx.x;
    if (blk >= CONVW_BLOCKS) {   // block-uniform branch: zeroing tail
        const int zi = (blk - CONVW_BLOCKS) * 256 + threadIdx.x;
        reinterpret_cast<float4*>(n2z)[zi] = float4{0.f, 0.f, 0.f, 0.f};
        return;
    }
    int k = (blk * 256 + threadIdx.x) * 2;   // even chunk index (NC_WV even)
    const float* src;
    __bf16* dst;
    if (k < NC_WV) { src = Wv; dst = Wvb; }
    else { k -= NC_WV; src = Wt; dst = Wtb; }
    const float4 x0 = reinterpret_cast<const float4*>(src)[k];
    const float4 x1 = reinterpret_cast<const float4*>(src)[k + 1];
    bf16x8 q = {(__bf16)x0.x, (__bf16)x0.y, (__bf16)x0.z, (__bf16)x0.w,
                (__bf16)x1.x, (__bf16)x1.y, (__bf16)x1.z, (__bf16)x1.w};
    reinterpret_cast<bf16x8*>(dst)[k >> 1] = q;
}

// ---------------------------------------------------------------------------
// Projection GEMM (NT), 256x256 tile, 512 threads (8 waves 2x4, wave 128x64),
// BK=64, TRIPLE-BUFFERED A (160 KiB LDS). [= VERIFIED round-7 kernel (76us),
// ONE edit: the 4 per-phase s_barriers are REMOVED -> 2 barriers/K-tile.]
// Why correct: intra-tile, all LDS reads target buffers published by the
// previous boundary's lgkmcnt(0)+barrier; intra-tile LDS writes (stA_chunk)
// target As[aw], which no wave reads this tile; B staging stays at the
// boundary behind barrier #1 (all Bs[kt&1] readers done). Per-wave reg deps
// are compiler-tracked. The phase barriers were scheduling-only — and R9
// showed the lockstep makes the slowest phase every wave's clock. Removing
// them lets waves desync so one wave's waits overlap another's MFMA (m114).
//   C[M][512] = X[M][K] * W[512][K]^T + bias -> bf16 + fused norm^2.
// ---------------------------------------------------------------------------
__global__ __launch_bounds__(512, 2) void proj_kernel(
    const float* __restrict__ Xv32, const __bf16* __restrict__ Wvb, const float* __restrict__ bv_,
    const float* __restrict__ Xt32, const __bf16* __restrict__ Wtb, const float* __restrict__ bt_,
    __bf16* __restrict__ vout, __bf16* __restrict__ tout,
    float* __restrict__ vn2, float* __restrict__ tn2)
{
    __shared__ __bf16 As[3][256 * 64];   // 96 KiB (triple buffer)
    __shared__ __bf16 Bs[2][256 * 64];   // 64 KiB -> 160 KiB total (CU max)

    const int L  = blockIdx.x;
    const int x  = L & 7;                // XCD
    const int s  = L >> 3;               // 0..31
    const int z  = s >> 4;               // 0 = visual, 1 = text
    const int ss = s & 15;
    const int m0 = (x * 8 + (ss >> 1)) * 256;
    const int n0 = (ss & 1) * 256;

    const float* X; const __bf16* Wb; const float* bias; __bf16* out; float* n2; int K;
    if (z == 0) { X = Xv32; Wb = Wvb; bias = bv_; out = vout; n2 = vn2; K = VD; }
    else        { X = Xt32; Wb = Wtb; bias = bt_; out = tout; n2 = tn2; K = TD; }

    const int tid  = threadIdx.x;
    const int lane = tid & 63;
    const int wave = tid >> 6;
    const int wr   = wave >> 2;          // 0..1  (128-row half)
    const int wc   = wave & 3;           // 0..3  (64-col quarter)
    const int fr   = lane & 15;
    const int fq   = lane >> 4;

    f32x4 acc[8][4] = {};
    const int NKT = K >> 6;              // 16 (v) / 12 (t), block-uniform

    float4 regs[8];                      // A(next-next) raw fp32, 32 VGPR
    // prologue: A0 via regs+cvt into As[0]; A1 loaded into regs; B0/B1 DMA.
    {
        float4 rA0[8];
        ldA_chunk(X, K, m0, 0, tid, 0, rA0);
        ldA_chunk(X, K, m0, 0, tid, 1, rA0);
        ldA_chunk(X, K, m0, 0, tid, 2, rA0);
        ldA_chunk(X, K, m0, 0, tid, 3, rA0);
        stage_tile256(Wb, K, n0, 0,  Bs[0], tid);
        stage_tile256(Wb, K, n0, 64, Bs[1], tid);
        // compiler auto-waits retire A0 (oldest 8) before the cvt reads;
        // B0/B1 DMAs (newer) stay in flight.
        stA_chunk(As[0], tid, 0, rA0);
        stA_chunk(As[0], tid, 1, rA0);
        stA_chunk(As[0], tid, 2, rA0);
        stA_chunk(As[0], tid, 3, rA0);
        if (1 < NKT) {
            ldA_chunk(X, K, m0, 64, tid, 0, regs);
            ldA_chunk(X, K, m0, 64, tid, 1, regs);
            ldA_chunk(X, K, m0, 64, tid, 2, regs);
            ldA_chunk(X, K, m0, 64, tid, 3, regs);
        }
        // queue: [B0 x4, B1 x4, A1 x8] -> vmcnt(12) retires B0.
        asm volatile("s_waitcnt vmcnt(12)" ::: "memory");
        asm volatile("s_waitcnt lgkmcnt(0)" ::: "memory");
        __builtin_amdgcn_s_barrier();
    }

    int ar = 0, aw = 1;                  // A read/write buffer indices (mod 3)
    for (int kt = 0; kt < NKT; ++kt) {
        const __bf16* Ab = As[ar];
        const __bf16* Bb = Bs[kt & 1];
        const int doW = (kt + 1 < NKT);  // write A(kt+1) this tile
        const int doL = (kt + 2 < NKT);  // load  A(kt+2) this tile
        bf16x8 bfr[4][2];                // B frags live across all 4 phases
#pragma unroll
        for (int q = 0; q < 4; ++q) {    // phase q: m-frags {2q,2q+1} x 4n x 2kh = 16 MFMA
            bf16x8 afr[2][2];
#pragma unroll
            for (int m2 = 0; m2 < 2; ++m2)
#pragma unroll
                for (int h = 0; h < 2; ++h)
                    afr[m2][h] = frag_read(Ab, wr * 128 + (q * 2 + m2) * 16 + fr, h, fq);
            if (q == 0) {
#pragma unroll
                for (int n = 0; n < 4; ++n)
#pragma unroll
                    for (int h = 0; h < 2; ++h)
                        bfr[n][h] = frag_read(Bb, wc * 64 + n * 16 + fr, h, fq);
            }
            // distributed A staging (uniform guards; regs WAR by issue order)
            if (doW) stA_chunk(As[aw], tid, q, regs);
            if (doL) ldA_chunk(X, K, m0, (kt + 2) << 6, tid, q, regs);
            // NO per-phase barrier (the R10 edit): waves free-run inside the
            // tile; cross-wave LDS safety is carried by the boundary pair.
            __builtin_amdgcn_s_setprio(1);
#pragma unroll
            for (int h = 0; h < 2; ++h)
#pragma unroll
                for (int m2 = 0; m2 < 2; ++m2)
#pragma unroll
                    for (int n = 0; n < 4; ++n)
                        acc[q * 2 + m2][n] = MFMA16(afr[m2][h], bfr[n][h], acc[q * 2 + m2][n]);
            __builtin_amdgcn_s_setprio(0);
        }
        // K-tile boundary
        if (kt < NKT - 1) {
            __builtin_amdgcn_s_barrier();           // all waves done reading
            __builtin_amdgcn_sched_barrier(0);
            if (kt + 2 < NKT) {
                stage_tile256(Wb, K, n0, (kt + 2) << 6, Bs[kt & 1], tid);
                // queue: [B(kt+1) x4, A(kt+2) x8, B(kt+2) x4] -> retire B(kt+1)
                asm volatile("s_waitcnt vmcnt(12)" ::: "memory");
            } else {
                asm volatile("s_waitcnt vmcnt(0)" ::: "memory");   // last B
            }
            asm volatile("s_waitcnt lgkmcnt(0)" ::: "memory");     // A writes visible
            __builtin_amdgcn_sched_barrier(0);
            __builtin_amdgcn_s_barrier();           // tile kt+1 fully resident
            ar = aw;
            aw = (aw == 2) ? 0 : aw + 1;
        }
    }

    // epilogue: +bias, bf16 store, fused partial row-norm^2
    float bc[4];
#pragma unroll
    for (int n = 0; n < 4; ++n)
        bc[n] = bias[n0 + wc * 64 + n * 16 + fr];

#pragma unroll
    for (int mf = 0; mf < 8; ++mf) {
        const int rowb = m0 + wr * 128 + mf * 16 + fq * 4;
#pragma unroll
        for (int r = 0; r < 4; ++r) {
            float s_ = 0.f;
#pragma unroll
            for (int n = 0; n < 4; ++n) {
                const float e = acc[mf][n][r] + bc[n];
                out[(size_t)(rowb + r) * HDIM + n0 + wc * 64 + n * 16 + fr] = (__bf16)e;
                s_ = fmaf(e, e, s_);
            }
            s_ += __shfl_xor(s_, 1);
            s_ += __shfl_xor(s_, 2);
            s_ += __shfl_xor(s_, 4);
            s_ += __shfl_xor(s_, 8);
            if (fr == 0) atomicAdd(&n2[rowb + r], s_);
        }
    }
}

// ---------------------------------------------------------------------------
// Batched dots GEMM (NT) -- 256x256 tile, 512 threads (8 waves 2x4, wave
// 128x64), BK=64, K=512 -> 8 K-tiles, double-buffered DMA staging with
// COUNTED vmcnt (T4) + 4-phase MFMA split + setprio (T3/T5) + raw s_barrier
// only.  out[b][i][j] = v.t / max(sqrt(vn2_i*tn2_j), eps)
// Grid: 256 blocks = 1/CU; XCD x owns batches {2x, 2x+1} (4MB = its L2).
// [FROZEN since round 2 -- control kernel]
// ---------------------------------------------------------------------------
__global__ __launch_bounds__(512, 2) void dots_kernel(const __bf16* __restrict__ v,
                                                      const __bf16* __restrict__ t,
                                                      const float* __restrict__ vn2,
                                                      const float* __restrict__ tn2,
                                                      float* __restrict__ out) {
    __shared__ __bf16 As[2][256 * 64];   // 64 KiB
    __shared__ __bf16 Bs[2][256 * 64];   // 64 KiB

    const int L  = blockIdx.x;
    const int x  = L & 7;
    const int s  = L >> 3;               // 0..31 within XCD
    const int b  = x * 2 + (s >> 4);     // batch
    const int i0 = ((s >> 2) & 3) * 256;
    const int j0 = (s & 3) * 256;

    const __bf16* vb = v + (size_t)b * SEQ * HDIM;
    const __bf16* tb = t + (size_t)b * SEQ * HDIM;

    const int tid  = threadIdx.x;
    const int lane = tid & 63;
    const int wave = tid >> 6;
    const int wr   = wave >> 2;          // 0..1  (128-row half)
    const int wc   = wave & 3;           // 0..3  (64-col quarter)
    const int fr   = lane & 15;
    const int fq   = lane >> 4;

    f32x4 acc[8][4] = {};
    const int NKT = HDIM >> 6;           // 8

    // prologue: stage K-tiles 0 and 1 (8 DMA loads/thread each)
    stage_tile256(vb, HDIM, i0, 0,  As[0], tid);
    stage_tile256(tb, HDIM, j0, 0,  Bs[0], tid);
    stage_tile256(vb, HDIM, i0, 64, As[1], tid);
    stage_tile256(tb, HDIM, j0, 64, Bs[1], tid);
    asm volatile("s_waitcnt vmcnt(8)" ::: "memory");  // K-tile 0 landed (in-order retire)
    __builtin_amdgcn_s_barrier();                     // all waves' tile-0 loads drained

    for (int kt = 0; kt < NKT; ++kt) {
        const __bf16* Ab = As[kt & 1];
        const __bf16* Bb = Bs[kt & 1];
        bf16x8 bfr[4][2];                // B frags live across all 4 phases
#pragma unroll
        for (int q = 0; q < 4; ++q) {    // phase q: m-frags {2q, 2q+1} x 4n x 2kh = 16 MFMA
            bf16x8 afr[2][2];
#pragma unroll
            for (int m2 = 0; m2 < 2; ++m2)
#pragma unroll
                for (int h = 0; h < 2; ++h)
                    afr[m2][h] = frag_read(Ab, wr * 128 + (q * 2 + m2) * 16 + fr, h, fq);
            if (q == 0) {
#pragma unroll
                for (int n = 0; n < 4; ++n)
#pragma unroll
                    for (int h = 0; h < 2; ++h)
                        bfr[n][h] = frag_read(Bb, wc * 64 + n * 16 + fr, h, fq);
            }
            __builtin_amdgcn_s_barrier();           // phase-entry lockstep
            __builtin_amdgcn_s_setprio(1);
#pragma unroll
            for (int h = 0; h < 2; ++h)
#pragma unroll
                for (int m2 = 0; m2 < 2; ++m2)
#pragma unroll
                    for (int n = 0; n < 4; ++n)
                        acc[q * 2 + m2][n] = MFMA16(afr[m2][h], bfr[n][h], acc[q * 2 + m2][n]);
            __builtin_amdgcn_s_setprio(0);
        }
        // K-tile boundary: buf[kt&1] fully consumed by ALL waves after this barrier.
        if (kt < NKT - 1) {
            __builtin_amdgcn_s_barrier();           // end of reads of buf[kt&1]
            __builtin_amdgcn_sched_barrier(0);
            if (kt + 2 < NKT) {
                const int kk = (kt + 2) << 6;
                stage_tile256(vb, HDIM, i0, kk, As[kt & 1], tid);
                stage_tile256(tb, HDIM, j0, kk, Bs[kt & 1], tid);
                // outstanding: stage(kt+1)=8 (oldest) + stage(kt+2)=8.
                // Leave kt+2 in flight across the whole next K-tile (T4).
                asm volatile("s_waitcnt vmcnt(8)" ::: "memory");
            } else {
                asm volatile("s_waitcnt vmcnt(0)" ::: "memory");
            }
            __builtin_amdgcn_sched_barrier(0);
            __builtin_amdgcn_s_barrier();           // all waves drained kt+1
        }
    }

    // epilogue: normalize and store fp32 output
    float vr2[8][4];
#pragma unroll
    for (int mf = 0; mf < 8; ++mf)
#pragma unroll
        for (int r = 0; r < 4; ++r)
            vr2[mf][r] = vn2[b * SEQ + i0 + wr * 128 + mf * 16 + fq * 4 + r];

    float* outb = out + ((size_t)b << 20);
#pragma unroll
    for (int n = 0; n < 4; ++n) {
        const int j     = j0 + wc * 64 + n * 16 + fr;
        const float tj2 = tn2[b * SEQ + j];
#pragma unroll
        for (int mf = 0; mf < 8; ++mf) {
            const int ib = i0 + wr * 128 + mf * 16 + fq * 4;
#pragma unroll
            for (int r = 0; r < 4; ++r) {
                const float denom = fmaxf(sqrtf(vr2[mf][r] * tj2), 1e-8f);
                outb[(size_t)(ib + r) * SEQ + j] = acc[mf][n][r] * __builtin_amdgcn_rcpf(denom);
            }
        }
    }
}

// ---------------------------------------------------------------------------
extern "C" void kernel_launch(void* const* d_in, const int* in_sizes, int n_in,
                              void* d_out, int out_size, void* d_ws, size_t ws_size,
                              hipStream_t stream) {
    const float* Xv = (const float*)d_in[0];
    const float* Xt = (const float*)d_in[1];
    const float* Wv = (const float*)d_in[2];
    const float* bv = (const float*)d_in[3];
    const float* Wt = (const float*)d_in[4];
    const float* bt = (const float*)d_in[5];
    float* out = (float*)d_out;

    char* ws = (char*)d_ws;
    size_t off = 0;
    __bf16* v   = (__bf16*)(ws + off); off += (size_t)MROWS * HDIM * 2;    // 16 MiB
    __bf16* t   = (__bf16*)(ws + off); off += (size_t)MROWS * HDIM * 2;    // 16 MiB
    __bf16* Wvb = (__bf16*)(ws + off); off += (size_t)HDIM * VD * 2;       // 1 MiB
    __bf16* Wtb = (__bf16*)(ws + off); off += (size_t)HDIM * TD * 2;       // 0.75 MiB
    float*  vn2 = (float*)(ws + off);  off += (size_t)MROWS * 4;           // 64 KiB
    float*  tn2 = (float*)(ws + off);  off += (size_t)MROWS * 4;           // 64 KiB (contiguous after vn2)

    // 0) W fp32 -> bf16 (tiny) + vn2/tn2 zero tail
    conv_w_kernel<<<CONVW_GRID, 256, 0, stream>>>(Wv, Wt, Wvb, Wtb, vn2);

    // 1) projections + fused norms (X converted in-staging): 256 blocks x 512
    proj_kernel<<<256, 512, 0, stream>>>(Xv, Wvb, bv, Xt, Wtb, bt, v, t, vn2, tn2);

    // 2) batched dots + normalize: 256 swizzled blocks of 512 threads
    dots_kernel<<<256, 512, 0, stream>>>(v, t, vn2, tn2, out);
}